// Round 9
// baseline (5138.366 us; speedup 1.0000x reference)
//
#include <hip/hip_runtime.h>
#include <hip/hip_bf16.h>
#include <stdint.h>

#define T_STEPS 256
#define HH      100
#define ROWS    16
#define BLK     512

typedef __bf16 bf16x8 __attribute__((ext_vector_type(8)));
typedef float  f32x4  __attribute__((ext_vector_type(4)));
typedef unsigned short ushort_t;

// A stream layout: unit = 16B = one lane's frag slice.
//   slot = ((mat*25 + mt)*4 + kt)*2 + part   (mat: 0=Whh1,1=Wih2,2=Whh2; part: 0=hi,1=lo)
//   unit = slot*64 + lane; lane's 8 bf16 = W[mt*16+(lane&15)][kt*32+(lane>>4)*8 + e] (0 if k>=100)
#define A_UNITS 38400            // 600 slots * 64
#define WS_AF   153600           // floats occupied by A (600*64*16B/4)
#define WS_B1   153600
#define WS_B2   154000
#define WS_WI   154400
#define WS_WL   154800
#define WS_BLIN 154900
#define WS_TOTAL 154901

__global__ __launch_bounds__(512) void pack_kernel(
    const float* __restrict__ Whh1, const float* __restrict__ Wih2,
    const float* __restrict__ Whh2,
    const float* __restrict__ bih1, const float* __restrict__ bhh1,
    const float* __restrict__ bih2, const float* __restrict__ bhh2,
    const float* __restrict__ Wih1, const float* __restrict__ Wlin,
    const float* __restrict__ blin, float* __restrict__ ws) {
  int idx = blockIdx.x * BLK + threadIdx.x;
  if (idx < A_UNITS) {
    int lane = idx & 63, slot = idx >> 6;
    int part = slot & 1, q = slot >> 1;
    int kt = q & 3, q2 = q >> 2;
    int mt = q2 % 25, mat = q2 / 25;
    const float* W = (mat == 0) ? Whh1 : (mat == 1) ? Wih2 : Whh2;
    int row = mt * 16 + (lane & 15);
    int kb  = kt * 32 + (lane >> 4) * 8;
    ushort_t* dst = (ushort_t*)ws + (size_t)slot * 512 + lane * 8;
#pragma unroll
    for (int e = 0; e < 8; ++e) {
      int k = kb + e;
      float w = (k < HH) ? W[row * HH + k] : 0.0f;
      __hip_bfloat16 hb = __float2bfloat16(w);
      ushort_t ub;
      if (part == 0) {
        __builtin_memcpy(&ub, &hb, 2);
      } else {
        float lo = w - __bfloat162float(hb);
        __hip_bfloat16 lb = __float2bfloat16(lo);
        __builtin_memcpy(&ub, &lb, 2);
      }
      dst[e] = ub;
    }
  } else if (idx < A_UNITS + 1301) {
    int o = idx - A_UNITS;
    float v;
    if (o < 400)       v = bih1[o] + bhh1[o];
    else if (o < 800)  v = bih2[o - 400] + bhh2[o - 400];
    else if (o < 1200) v = Wih1[o - 800];
    else if (o < 1300) v = Wlin[o - 1200];
    else               v = blin[0];
    ws[WS_AF + o] = v;
  }
}

__device__ __forceinline__ float sigf(float v) {
  return 1.0f / (1.0f + __expf(-v));
}
__device__ __forceinline__ float tanh_fast(float v) {
  float t = __expf(2.0f * v);
  return 1.0f - 2.0f / (t + 1.0f);
}

#define BAR()                                                 \
  do {                                                        \
    asm volatile("s_waitcnt lgkmcnt(0)" ::: "memory");        \
    __builtin_amdgcn_s_barrier();                             \
  } while (0)

#define LOADB(HI, LO)                                                     \
  _Pragma("unroll")                                                       \
  for (int kt = 0; kt < 4; ++kt) {                                        \
    __builtin_memcpy(&bh[kt], &hB[HI][boff[kt]], 16);                     \
    __builtin_memcpy(&bl[kt], &hB[LO][boff[kt]], 16);                     \
  }

#define LOADA(MAT, MT)                                                    \
  _Pragma("unroll")                                                       \
  for (int kt = 0; kt < 4; ++kt) {                                        \
    size_t u0 = ((((size_t)(MAT) * 25 + (MT)) * 4 + kt) * 2) * 64 + lane; \
    __builtin_memcpy(&ah[kt], Ab + u0 * 16, 16);                          \
    __builtin_memcpy(&al[kt], Ab + (u0 + 64) * 16, 16);                   \
  }

#define MFMA12()                                                          \
  do {                                                                    \
    p0 = (f32x4){0, 0, 0, 0}; p1 = p0; p2 = p0;                           \
    _Pragma("unroll")                                                     \
    for (int kt = 0; kt < 4; ++kt) {                                      \
      p0 = __builtin_amdgcn_mfma_f32_16x16x32_bf16(ah[kt], bh[kt], p0, 0, 0, 0); \
      p1 = __builtin_amdgcn_mfma_f32_16x16x32_bf16(ah[kt], bl[kt], p1, 0, 0, 0); \
      p2 = __builtin_amdgcn_mfma_f32_16x16x32_bf16(al[kt], bh[kt], p2, 0, 0, 0); \
    }                                                                     \
  } while (0)

__global__ __launch_bounds__(512) void lstm_persist(
    const float* __restrict__ x, const float* __restrict__ ws,
    float* __restrict__ out, int T) {
  // hB: 0=h1 hi, 1=h1 lo, 2=h2 hi, 3=h2 lo; [16 n-rows][128 k] bf16,
  // slot-swizzled: phys_slot = (k>>3) ^ (row&7). Pad (k>=100, rows unused)
  // zero-initialized and never rewritten (A pad is zero too -> no NaN).
  __shared__ __align__(16) ushort_t hB[4][2048];
  __shared__ __align__(16) float gbp[16][404];
  __shared__ float h2f[16][HH];
  __shared__ float b1s[400], b2s[400], wis[400], wls[HH], xs[ROWS];

  const int tid = threadIdx.x;
  const int r0  = blockIdx.x * ROWS;

  for (int i = tid; i < 4096; i += BLK) ((uint32_t*)hB)[i] = 0u;
  if (tid < 400) {
    b1s[tid] = ws[WS_B1 + tid];
    b2s[tid] = ws[WS_B2 + tid];
    wis[tid] = ws[WS_WI + tid];
  }
  if (tid < HH) wls[tid] = ws[WS_WL + tid];
  if (tid < ROWS) xs[tid] = x[(size_t)(r0 + tid) * T];
  __syncthreads();

  const int wid  = tid >> 6, lane = tid & 63;
  const int brow = lane & 15, bg = lane >> 4;
  const int gate0 = bg * 4;
  int boff[4];
#pragma unroll
  for (int kt = 0; kt < 4; ++kt)
    boff[kt] = brow * 128 + ((((kt << 2) + bg) ^ (brow & 7)) << 3);
  const int nmt = (wid == 0) ? 4 : 3;   // wave w owns mt = w, w+8, w+16 (+24 for w=0)
  const char* Ab = (const char*)ws;

  // act: element e = tid + 512p, e<1600: (row er, unit en)
  int er_[4], en_[4], wof_[4];
#pragma unroll
  for (int p = 0; p < 4; ++p) {
    int e = tid + BLK * p;
    int er = e / 100, en = e - er * 100;
    er_[p] = er; en_[p] = en;
    wof_[p] = er * 128 + (((en >> 3) ^ (er & 7)) << 3) + (en & 7);
  }
  const bool v3 = (tid < 1600 - 3 * BLK);
  float c1[4] = {0, 0, 0, 0}, c2[4] = {0, 0, 0, 0};

#pragma unroll 1
  for (int t = 0; t < T; ++t) {
    // ========== phase 1: g1 = Whh1 @ h1(t-1) ==========
    {
      bf16x8 bh[4], bl[4], ah[4], al[4];
      f32x4 p0, p1, p2;
      LOADB(0, 1);
#pragma unroll
      for (int i = 0; i < 4; ++i)
        if (i < nmt) {
          int mt = wid + 8 * i;
          LOADA(0, mt);
          MFMA12();
          f32x4 s = p0 + p1 + p2;
          *(f32x4*)&gbp[brow][mt * 16 + gate0] = s;
        }
    }
    BAR();

    // ========== act 1 ==========
#pragma unroll
    for (int p = 0; p < 4; ++p)
      if (p < 3 || v3) {
        int er = er_[p], en = en_[p];
        float xv = xs[er];
        float g0 = gbp[er][en]       + b1s[en]       + wis[en] * xv;
        float g1 = gbp[er][en + 100] + b1s[en + 100] + wis[en + 100] * xv;
        float g2 = gbp[er][en + 200] + b1s[en + 200] + wis[en + 200] * xv;
        float g3 = gbp[er][en + 300] + b1s[en + 300] + wis[en + 300] * xv;
        float iv = sigf(g0), fv = sigf(g1), gv = tanh_fast(g2), ov = sigf(g3);
        c1[p] = fv * c1[p] + iv * gv;
        float h = ov * tanh_fast(c1[p]);
        __hip_bfloat16 hb = __float2bfloat16(h);
        ushort_t ub; __builtin_memcpy(&ub, &hb, 2);
        hB[0][wof_[p]] = ub;
        float lo = h - __bfloat162float(hb);
        __hip_bfloat16 lb = __float2bfloat16(lo);
        __builtin_memcpy(&ub, &lb, 2);
        hB[1][wof_[p]] = ub;
      }
    BAR();

    // ========== phase 3: g2 = Wih2 @ h1(t) + Whh2 @ h2(t-1) ==========
    {
      bf16x8 bh[4], bl[4], ah[4], al[4];
      f32x4 p0, p1, p2;
      LOADB(0, 1);   // h1 new
#pragma unroll
      for (int i = 0; i < 4; ++i)
        if (i < nmt) {
          int mt = wid + 8 * i;
          LOADA(1, mt);
          MFMA12();
          f32x4 s = p0 + p1 + p2;
          *(f32x4*)&gbp[brow][mt * 16 + gate0] = s;
        }
      LOADB(2, 3);   // h2 old
#pragma unroll
      for (int i = 0; i < 4; ++i)
        if (i < nmt) {
          int mt = wid + 8 * i;
          LOADA(2, mt);
          MFMA12();
          f32x4 o;
          __builtin_memcpy(&o, &gbp[brow][mt * 16 + gate0], 16);
          o += p0 + p1 + p2;   // same lane wrote it above: same-wave DS order
          *(f32x4*)&gbp[brow][mt * 16 + gate0] = o;
        }
    }
    BAR();

    // ========== act 2 + x prefetch ==========
#pragma unroll
    for (int p = 0; p < 4; ++p)
      if (p < 3 || v3) {
        int er = er_[p], en = en_[p];
        float g0 = gbp[er][en]       + b2s[en];
        float g1 = gbp[er][en + 100] + b2s[en + 100];
        float g2 = gbp[er][en + 200] + b2s[en + 200];
        float g3 = gbp[er][en + 300] + b2s[en + 300];
        float iv = sigf(g0), fv = sigf(g1), gv = tanh_fast(g2), ov = sigf(g3);
        c2[p] = fv * c2[p] + iv * gv;
        float h = ov * tanh_fast(c2[p]);
        h2f[er][en] = h;
        __hip_bfloat16 hb = __float2bfloat16(h);
        ushort_t ub; __builtin_memcpy(&ub, &hb, 2);
        hB[2][wof_[p]] = ub;
        float lo = h - __bfloat162float(hb);
        __hip_bfloat16 lb = __float2bfloat16(lo);
        __builtin_memcpy(&ub, &lb, 2);
        hB[3][wof_[p]] = ub;
      }
    if (tid < ROWS && (t + 1) < T) xs[tid] = x[(size_t)(r0 + tid) * T + t + 1];
    BAR();
  }

  // ========== output: out[r] = h2f[r]·wlin + blin ==========
  {
    int row = tid >> 5, l32 = tid & 31;
    float p = 0.0f;
#pragma unroll
    for (int k = 0; k < 4; ++k) {
      int n = l32 + 32 * k;
      if (n < HH) p += h2f[row][n] * wls[n];
    }
#pragma unroll
    for (int off = 16; off > 0; off >>= 1) p += __shfl_down(p, off, 32);
    if (l32 == 0) out[r0 + row] = p + ws[WS_BLIN];
  }
}

// ---------------- launcher ----------------
extern "C" void kernel_launch(void* const* d_in, const int* in_sizes, int n_in,
                              void* d_out, int out_size, void* d_ws, size_t ws_size,
                              hipStream_t stream) {
  const float* x    = (const float*)d_in[0];
  const float* Wih1 = (const float*)d_in[1];
  const float* Whh1 = (const float*)d_in[2];
  const float* bih1 = (const float*)d_in[3];
  const float* bhh1 = (const float*)d_in[4];
  const float* Wih2 = (const float*)d_in[5];
  const float* Whh2 = (const float*)d_in[6];
  const float* bih2 = (const float*)d_in[7];
  const float* bhh2 = (const float*)d_in[8];
  const float* Wlin = (const float*)d_in[9];
  const float* blin = (const float*)d_in[10];

  float* ws  = (float*)d_ws;
  float* out = (float*)d_out;

  const int B = in_sizes[0] / T_STEPS;   // 2048

  pack_kernel<<<(A_UNITS + 1301 + BLK - 1) / BLK, BLK, 0, stream>>>(
      Whh1, Wih2, Whh2, bih1, bhh1, bih2, bhh2, Wih1, Wlin, blin, ws);

  lstm_persist<<<B / ROWS, BLK, 0, stream>>>(x, ws, out, T_STEPS);
}

// Round 10
// 5097.690 us; speedup vs baseline: 1.0080x; 1.0080x over previous
//
#include <hip/hip_runtime.h>
#include <hip/hip_bf16.h>
#include <stdint.h>

#define T_STEPS 256
#define HH      100
#define ROWS    8
#define BLK     512

typedef __bf16 bf16x8 __attribute__((ext_vector_type(8)));
typedef float  f32x4  __attribute__((ext_vector_type(4)));
typedef unsigned short ushort_t;
typedef const __attribute__((address_space(1))) uint32_t gu32;
typedef __attribute__((address_space(3))) uint32_t lu32;

// A layout (same as R9, verified): slot = (mat*25 + mt)*8 + kt*2 + part
// unit = slot = 1KB: lane's 8 bf16 = W_mat[mt*16+(lane&15)][kt*32+(lane>>4)*8+e]
// (0 if k>=100). part: 0=hi, 1=lo (exact bf16 residual split).
#define A_UNITS 38400            // 600 slots * 64 lanes
#define WS_B1   153600
#define WS_B2   154000
#define WS_WI   154400
#define WS_WL   154800
#define WS_BLIN 154900

__global__ __launch_bounds__(512) void pack_kernel(
    const float* __restrict__ Whh1, const float* __restrict__ Wih2,
    const float* __restrict__ Whh2,
    const float* __restrict__ bih1, const float* __restrict__ bhh1,
    const float* __restrict__ bih2, const float* __restrict__ bhh2,
    const float* __restrict__ Wih1, const float* __restrict__ Wlin,
    const float* __restrict__ blin, float* __restrict__ ws) {
  int idx = blockIdx.x * BLK + threadIdx.x;
  if (idx < A_UNITS) {
    int lane = idx & 63, slot = idx >> 6;
    int part = slot & 1, q = slot >> 1;
    int kt = q & 3, q2 = q >> 2;
    int mt = q2 % 25, mat = q2 / 25;
    const float* W = (mat == 0) ? Whh1 : (mat == 1) ? Wih2 : Whh2;
    int row = mt * 16 + (lane & 15);
    int kb  = kt * 32 + (lane >> 4) * 8;
    ushort_t* dst = (ushort_t*)ws + (size_t)slot * 512 + lane * 8;
#pragma unroll
    for (int e = 0; e < 8; ++e) {
      int k = kb + e;
      float w = (k < HH) ? W[row * HH + k] : 0.0f;
      __hip_bfloat16 hb = __float2bfloat16(w);
      ushort_t ub;
      if (part == 0) {
        __builtin_memcpy(&ub, &hb, 2);
      } else {
        float lo = w - __bfloat162float(hb);
        __hip_bfloat16 lb = __float2bfloat16(lo);
        __builtin_memcpy(&ub, &lb, 2);
      }
      dst[e] = ub;
    }
  } else if (idx < A_UNITS + 1301) {
    int o = idx - A_UNITS;
    float v;
    if (o < 400)       v = bih1[o] + bhh1[o];
    else if (o < 800)  v = bih2[o - 400] + bhh2[o - 400];
    else if (o < 1200) v = Wih1[o - 800];
    else if (o < 1300) v = Wlin[o - 1200];
    else               v = blin[0];
    ws[WS_B1 + o] = v;
  }
}

__device__ __forceinline__ float sigf(float v) {
  return 1.0f / (1.0f + __expf(-v));
}
__device__ __forceinline__ float tanh_fast(float v) {
  float t = __expf(2.0f * v);
  return 1.0f - 2.0f / (t + 1.0f);
}

// LDS map (floats)
#define L_RING 0                    // 8 waves * 8 slabs * 256 = 16384
#define L_HB   16384                // 4 planes * 2048 ushort  = 4096 floats
#define L_GBP  20480                // [8][404]                = 3232
#define L_H2F  23712                // [8][100]
#define L_B1   24512
#define L_B2   24912
#define L_WI   25312
#define L_WL   25712
#define L_X    25812                // [8][256]
#define L_TOT  27860                // 111440 B

// lgkmcnt-only barrier: A-DMAs (vmcnt) stay in flight across phases.
#define BAR() do { asm volatile("s_waitcnt lgkmcnt(0)" ::: "memory"); \
                   __builtin_amdgcn_s_barrier(); } while (0)

// mt owned by this wave at list position I (compile-time I, runtime wid)
#define MTV(I)      ((I) < 3 ? 3 * wid + (I) : 24)
#define SBASE(M, I) (((M) * 25 + MTV(I)) * 8)

#define STAGE(SLOT, SLAB)                                                     \
  __builtin_amdgcn_global_load_lds(                                           \
      (gu32*)(Ab + (size_t)(SLOT)*1024 + lb),                                 \
      (lu32*)(myring + (SLAB)*256), 16, 0, 0)

#define LOADB(HI, LO)                                                         \
  _Pragma("unroll")                                                           \
  for (int kt = 0; kt < 4; ++kt) {                                            \
    __builtin_memcpy(&bh[kt], &hB[(HI)*2048 + boff[kt]], 16);                 \
    __builtin_memcpy(&bl[kt], &hB[(LO)*2048 + boff[kt]], 16);                 \
  }

// one mt-group: 8 units consumed from ring (slab j), stage 4-ahead, 12 MFMAs
#define GROUP(I, SBC, SBN, RMW)                                               \
  do {                                                                        \
    f32x4 q0 = {0, 0, 0, 0}, q1 = q0, q2 = q0;                                \
    _Pragma("unroll")                                                         \
    for (int j = 0; j < 8; ++j) {                                             \
      if (j < 4) STAGE((SBC) + j + 4, j + 4);                                 \
      else       STAGE((SBN) + j - 4, j - 4);                                 \
      asm volatile("s_waitcnt vmcnt(4)" ::: "memory");                        \
      bf16x8 fr; __builtin_memcpy(&fr, myring + j * 256 + lane * 4, 16);      \
      const int kt_ = j >> 1;                                                 \
      if ((j & 1) == 0) {                                                     \
        q0 = __builtin_amdgcn_mfma_f32_16x16x32_bf16(fr, bh[kt_], q0, 0,0,0); \
        q1 = __builtin_amdgcn_mfma_f32_16x16x32_bf16(fr, bl[kt_], q1, 0,0,0); \
      } else {                                                                \
        q2 = __builtin_amdgcn_mfma_f32_16x16x32_bf16(fr, bh[kt_], q2, 0,0,0); \
      }                                                                       \
    }                                                                         \
    if (brow < 8) {                                                           \
      f32x4 s_ = q0 + q1 + q2;                                                \
      float* gp = &gbp[brow * 404 + MTV(I) * 16 + gate0];                     \
      if (RMW) { f32x4 o_; __builtin_memcpy(&o_, gp, 16); s_ += o_; }         \
      __builtin_memcpy(gp, &s_, 16);                                          \
    }                                                                         \
  } while (0)

__global__ __launch_bounds__(512) void lstm_persist(
    const float* __restrict__ x, const float* __restrict__ ws,
    float* __restrict__ out, int T) {
  extern __shared__ float sm[];
  float*    ring = sm + L_RING;
  ushort_t* hB   = (ushort_t*)(sm + L_HB);
  float*    gbp  = sm + L_GBP;
  float*    h2f  = sm + L_H2F;
  float*    b1s  = sm + L_B1;
  float*    b2s  = sm + L_B2;
  float*    wis  = sm + L_WI;
  float*    wls  = sm + L_WL;
  float*    xall = sm + L_X;

  const int tid = threadIdx.x;
  const int r0  = blockIdx.x * ROWS;

  // ---- init: zero hB (incl. row/k pads), stage consts, preload ALL x ----
  for (int i = tid; i < 4096; i += BLK) ((uint32_t*)hB)[i] = 0u;
  if (tid < 400) {
    b1s[tid] = ws[WS_B1 + tid];
    b2s[tid] = ws[WS_B2 + tid];
    wis[tid] = ws[WS_WI + tid];
  }
  if (tid < HH) wls[tid] = ws[WS_WL + tid];
#pragma unroll
  for (int p = 0; p < 4; ++p) {
    int e = tid + BLK * p;                       // 0..2047
    xall[e] = x[(size_t)r0 * T_STEPS + e];       // block rows contiguous
  }

  const int wid  = tid >> 6, lane = tid & 63;
  const int brow = lane & 15, bg = lane >> 4;
  const int gate0 = bg * 4;
  int boff[4];
#pragma unroll
  for (int kt = 0; kt < 4; ++kt)
    boff[kt] = brow * 128 + ((((kt << 2) + bg) ^ (brow & 7)) << 3);
  const int nmt = (wid == 7) ? 4 : 3;
  const char* Ab = (const char*)ws;
  float* myring = ring + wid * 2048;
  const int lb = lane * 16;

  // act-phase element mapping: pass0 e=tid (<800 always), pass1 e=tid+512
  const int e0r = tid / 100, e0n = tid - e0r * 100;
  const int e1  = tid + 512;
  const int e1r = e1 / 100, e1n = e1 - e1r * 100;
  const bool a1 = (e1 < ROWS * HH);
  const int wof0 = e0r * 128 + (((e0n >> 3) ^ (e0r & 7)) << 3) + (e0n & 7);
  const int wof1 = e1r * 128 + (((e1n >> 3) ^ (e1r & 7)) << 3) + (e1n & 7);
  float c1a = 0.f, c1b = 0.f, c2a = 0.f, c2b = 0.f;

  // ---- DMA prologue: units 0..3 of first group (mat0, i=0) ----
  {
    const int sb0 = SBASE(0, 0);
    STAGE(sb0 + 0, 0); STAGE(sb0 + 1, 1); STAGE(sb0 + 2, 2); STAGE(sb0 + 3, 3);
  }
  __syncthreads();   // init barrier (drains prologue DMAs — they are complete, not lost)

  bf16x8 bh[4], bl[4];

#pragma unroll 1
  for (int t = 0; t < T; ++t) {
    // ===== phase 1: g1 = Whh1 @ h1(t-1)  (mat 0) =====
    {
      LOADB(0, 1);
      int sbc = SBASE(0, 0), sbn = SBASE(0, 1);
      GROUP(0, sbc, sbn, 0);
      sbc = sbn; sbn = SBASE(0, 2);
      GROUP(1, sbc, sbn, 0);
      sbc = sbn; sbn = (nmt == 4) ? SBASE(0, 3) : SBASE(1, 0);
      GROUP(2, sbc, sbn, 0);
      if (nmt == 4) { sbc = sbn; sbn = SBASE(1, 0); GROUP(3, sbc, sbn, 0); }
    }
    BAR();

    // ===== act 1 =====
    {
      {
        float xv = xall[e0r * 256 + t];
        float g0 = gbp[e0r * 404 + e0n]       + b1s[e0n]       + wis[e0n] * xv;
        float g1 = gbp[e0r * 404 + e0n + 100] + b1s[e0n + 100] + wis[e0n + 100] * xv;
        float g2 = gbp[e0r * 404 + e0n + 200] + b1s[e0n + 200] + wis[e0n + 200] * xv;
        float g3 = gbp[e0r * 404 + e0n + 300] + b1s[e0n + 300] + wis[e0n + 300] * xv;
        float iv = sigf(g0), fv = sigf(g1), gv = tanh_fast(g2), ov = sigf(g3);
        c1a = fv * c1a + iv * gv;
        float h = ov * tanh_fast(c1a);
        __hip_bfloat16 hb_ = __float2bfloat16(h);
        ushort_t ub; __builtin_memcpy(&ub, &hb_, 2);
        hB[wof0] = ub;
        float lo = h - __bfloat162float(hb_);
        __hip_bfloat16 lb_ = __float2bfloat16(lo);
        __builtin_memcpy(&ub, &lb_, 2);
        hB[2048 + wof0] = ub;
      }
      if (a1) {
        float xv = xall[e1r * 256 + t];
        float g0 = gbp[e1r * 404 + e1n]       + b1s[e1n]       + wis[e1n] * xv;
        float g1 = gbp[e1r * 404 + e1n + 100] + b1s[e1n + 100] + wis[e1n + 100] * xv;
        float g2 = gbp[e1r * 404 + e1n + 200] + b1s[e1n + 200] + wis[e1n + 200] * xv;
        float g3 = gbp[e1r * 404 + e1n + 300] + b1s[e1n + 300] + wis[e1n + 300] * xv;
        float iv = sigf(g0), fv = sigf(g1), gv = tanh_fast(g2), ov = sigf(g3);
        c1b = fv * c1b + iv * gv;
        float h = ov * tanh_fast(c1b);
        __hip_bfloat16 hb_ = __float2bfloat16(h);
        ushort_t ub; __builtin_memcpy(&ub, &hb_, 2);
        hB[wof1] = ub;
        float lo = h - __bfloat162float(hb_);
        __hip_bfloat16 lb_ = __float2bfloat16(lo);
        __builtin_memcpy(&ub, &lb_, 2);
        hB[2048 + wof1] = ub;
      }
    }
    BAR();

    // ===== phase 3: g2 = Wih2 @ h1(t) + Whh2 @ h2(t-1)  (mats 1, 2) =====
    {
      LOADB(0, 1);
      int sbc = SBASE(1, 0), sbn = SBASE(1, 1);
      GROUP(0, sbc, sbn, 0);
      sbc = sbn; sbn = SBASE(1, 2);
      GROUP(1, sbc, sbn, 0);
      sbc = sbn; sbn = (nmt == 4) ? SBASE(1, 3) : SBASE(2, 0);
      GROUP(2, sbc, sbn, 0);
      if (nmt == 4) { sbc = sbn; sbn = SBASE(2, 0); GROUP(3, sbc, sbn, 0); }

      LOADB(2, 3);
      sbc = SBASE(2, 0); sbn = SBASE(2, 1);
      GROUP(0, sbc, sbn, 1);
      sbc = sbn; sbn = SBASE(2, 2);
      GROUP(1, sbc, sbn, 1);
      sbc = sbn; sbn = (nmt == 4) ? SBASE(2, 3) : SBASE(0, 0);   // wrap to next step
      GROUP(2, sbc, sbn, 1);
      if (nmt == 4) { sbc = sbn; sbn = SBASE(0, 0); GROUP(3, sbc, sbn, 1); }
    }
    BAR();

    // ===== act 2 =====
    {
      {
        float g0 = gbp[e0r * 404 + e0n]       + b2s[e0n];
        float g1 = gbp[e0r * 404 + e0n + 100] + b2s[e0n + 100];
        float g2 = gbp[e0r * 404 + e0n + 200] + b2s[e0n + 200];
        float g3 = gbp[e0r * 404 + e0n + 300] + b2s[e0n + 300];
        float iv = sigf(g0), fv = sigf(g1), gv = tanh_fast(g2), ov = sigf(g3);
        c2a = fv * c2a + iv * gv;
        float h = ov * tanh_fast(c2a);
        h2f[e0r * 100 + e0n] = h;
        __hip_bfloat16 hb_ = __float2bfloat16(h);
        ushort_t ub; __builtin_memcpy(&ub, &hb_, 2);
        hB[2 * 2048 + wof0] = ub;
        float lo = h - __bfloat162float(hb_);
        __hip_bfloat16 lb_ = __float2bfloat16(lo);
        __builtin_memcpy(&ub, &lb_, 2);
        hB[3 * 2048 + wof0] = ub;
      }
      if (a1) {
        float g0 = gbp[e1r * 404 + e1n]       + b2s[e1n];
        float g1 = gbp[e1r * 404 + e1n + 100] + b2s[e1n + 100];
        float g2 = gbp[e1r * 404 + e1n + 200] + b2s[e1n + 200];
        float g3 = gbp[e1r * 404 + e1n + 300] + b2s[e1n + 300];
        float iv = sigf(g0), fv = sigf(g1), gv = tanh_fast(g2), ov = sigf(g3);
        c2b = fv * c2b + iv * gv;
        float h = ov * tanh_fast(c2b);
        h2f[e1r * 100 + e1n] = h;
        __hip_bfloat16 hb_ = __float2bfloat16(h);
        ushort_t ub; __builtin_memcpy(&ub, &hb_, 2);
        hB[2 * 2048 + wof1] = ub;
        float lo = h - __bfloat162float(hb_);
        __hip_bfloat16 lb_ = __float2bfloat16(lo);
        __builtin_memcpy(&ub, &lb_, 2);
        hB[3 * 2048 + wof1] = ub;
      }
    }
    BAR();
  }

  // ===== output: out[r] = h2f[r]·wlin + blin =====
  {
    int row = tid >> 5, l32 = tid & 31;
    if (row < ROWS) {
      float p = 0.0f;
#pragma unroll
      for (int k = 0; k < 4; ++k) {
        int n = l32 + 32 * k;
        if (n < HH) p += h2f[row * 100 + n] * wls[n];
      }
#pragma unroll
      for (int off = 16; off > 0; off >>= 1) p += __shfl_down(p, off, 32);
      if (l32 == 0) out[r0 + row] = p + ws[WS_BLIN];
    }
  }
}

// ---------------- launcher ----------------
extern "C" void kernel_launch(void* const* d_in, const int* in_sizes, int n_in,
                              void* d_out, int out_size, void* d_ws, size_t ws_size,
                              hipStream_t stream) {
  const float* x    = (const float*)d_in[0];
  const float* Wih1 = (const float*)d_in[1];
  const float* Whh1 = (const float*)d_in[2];
  const float* bih1 = (const float*)d_in[3];
  const float* bhh1 = (const float*)d_in[4];
  const float* Wih2 = (const float*)d_in[5];
  const float* Whh2 = (const float*)d_in[6];
  const float* bih2 = (const float*)d_in[7];
  const float* bhh2 = (const float*)d_in[8];
  const float* Wlin = (const float*)d_in[9];
  const float* blin = (const float*)d_in[10];

  float* ws  = (float*)d_ws;
  float* out = (float*)d_out;

  const int B = in_sizes[0] / T_STEPS;   // 2048

  pack_kernel<<<(A_UNITS + 1301 + BLK - 1) / BLK, BLK, 0, stream>>>(
      Whh1, Wih2, Whh2, bih1, bhh1, bih2, bhh2, Wih1, Wlin, blin, ws);

  lstm_persist<<<B / ROWS, BLK, L_TOT * 4, stream>>>(x, ws, out, T_STEPS);
}